// Round 8
// baseline (305.920 us; speedup 1.0000x reference)
//
#include <hip/hip_runtime.h>
#include <math.h>

#define NB 64
#define NT 512
#define NVAR 16
#define VDIM 16
#define DD 64
#define FF 256
#define BT (NB*NT)
#define LN_EPS 1e-3f

typedef __attribute__((ext_vector_type(8))) short bf8;   // 8 bf16 = one MFMA A/B operand
typedef __attribute__((ext_vector_type(4))) float f4;
typedef __attribute__((ext_vector_type(4))) int i4;
typedef __attribute__((ext_vector_type(4))) unsigned u4;

// ---- ws layout (bytes) ----
#define CPROJ_OFF   0                        // 64*16*64 f32 = 256KB
#define RBIAS_OFF   262144                   // 64*16*64 f32 = 256KB  (bp - cproj@Wp)
#define WTP_OFF     524288                   // 16 vars x 4 frags x 64 x 16B = 64KB
#define BIGP_OFF    (524288+65536)           // 16 vars x 4 mats x 16 frags x 64 x 16B = 1MB
#define WSP_OFF     (524288+65536+1048576)   // 16 frags x 64 x 16B = 16KB
// mats: 0=Wp 1=W1 2=W2 3=Wg

// RNE fp32 -> bf16 split. hi = RNE(x); lo = x - hi.
__device__ __forceinline__ void split1(float x, unsigned &hb, float &lo) {
    unsigned u = __builtin_bit_cast(unsigned, x);
    unsigned r = u + 0x7fffu + ((u >> 16) & 1u);
    hb = r >> 16;
    lo = x - __builtin_bit_cast(float, r & 0xffff0000u);
}
__device__ __forceinline__ unsigned rnepk(float x, float y) {
    unsigned a = __builtin_bit_cast(unsigned, x);
    unsigned b = __builtin_bit_cast(unsigned, y);
    a = a + 0x7fffu + ((a >> 16) & 1u);
    b = b + 0x7fffu + ((b >> 16) & 1u);
    return (a >> 16) | (b & 0xffff0000u);
}
// truncation pack for lo parts (lo ~2^-9 of x; trunc error ~2^-17 of x)
__device__ __forceinline__ unsigned trpk(float x, float y) {
    unsigned a = __builtin_bit_cast(unsigned, x);
    unsigned b = __builtin_bit_cast(unsigned, y);
    return (a >> 16) | (b & 0xffff0000u);
}
// precise split (prep / packing, done once)
__device__ __forceinline__ void split4(f4 v, unsigned &h0, unsigned &h1,
                                       unsigned &l0, unsigned &l1) {
    unsigned b0,b1,b2,b3; float q0,q1,q2,q3;
    split1(v.x,b0,q0); split1(v.y,b1,q1); split1(v.z,b2,q2); split1(v.w,b3,q3);
    h0 = b0 | (b1<<16); h1 = b2 | (b3<<16);
    l0 = rnepk(q0,q1); l1 = rnepk(q2,q3);
}
// fast split (hot path: RNE hi, truncated lo)
__device__ __forceinline__ void split4f(f4 v, unsigned &h0, unsigned &h1,
                                        unsigned &l0, unsigned &l1) {
    unsigned b0,b1,b2,b3; float q0,q1,q2,q3;
    split1(v.x,b0,q0); split1(v.y,b1,q1); split1(v.z,b2,q2); split1(v.w,b3,q3);
    h0 = b0 | (b1<<16); h1 = b2 | (b3<<16);
    l0 = trpk(q0,q1); l1 = trpk(q2,q3);
}
// A operand = packed u4 verbatim: slots 0..3 = W_hi, slots 4..7 = W_lo
__device__ __forceinline__ bf8 afrag(u4 w) { return __builtin_bit_cast(bf8, w); }
// B operands for the 2-mfma split: [x_h|x_h] and [x_l|0]
__device__ __forceinline__ bf8 mk_bhh(unsigned h0, unsigned h1) {
    i4 t; t.x = (int)h0; t.y = (int)h1; t.z = (int)h0; t.w = (int)h1;
    return __builtin_bit_cast(bf8, t);
}
__device__ __forceinline__ bf8 mk_bl0(unsigned l0, unsigned l1) {
    i4 t; t.x = (int)l0; t.y = (int)l1; t.z = 0; t.w = 0;
    return __builtin_bit_cast(bf8, t);
}
__device__ __forceinline__ float bflo(unsigned w){ return __builtin_bit_cast(float, w<<16); }
__device__ __forceinline__ float bfhi(unsigned w){ return __builtin_bit_cast(float, w & 0xffff0000u); }

// 2-mfma split: A=[Wh|Wl] with Bh=[xh|xh] gives Wh*xh + Wl*xh; Bl=[xl|0] adds Wh*xl.
__device__ __forceinline__ f4 mfma2(f4 acc, bf8 Af, bf8 Bh, bf8 Bl) {
    acc = __builtin_amdgcn_mfma_f32_16x16x32_bf16(Af, Bh, acc, 0,0,0);
    acc = __builtin_amdgcn_mfma_f32_16x16x32_bf16(Af, Bl, acc, 0,0,0);
    return acc;
}

// acc (C-layout) -> B-operand frags of the next stage (pure in-lane repack)
__device__ __forceinline__ void acc_to_frags1(const f4 acc[4],
        unsigned fh[4][2], unsigned fl[4][2]) {
    #pragma unroll
    for (int Ks = 0; Ks < 4; ++Ks)
        split4f(acc[Ks], fh[Ks][0], fh[Ks][1], fl[Ks][0], fl[Ks][1]);
}
// One 64x64 GEMM-stage: acc[Mi] += Wpack^T . Bfrags  (2-mfma split)
__device__ __forceinline__ void run_stage2(const u4* __restrict__ ap, int lane,
        const unsigned fh[4][2], const unsigned fl[4][2], f4 acc[4]) {
    #pragma unroll 2
    for (int Ks = 0; Ks < 4; ++Ks) {
        bf8 Bh = mk_bhh(fh[Ks][0], fh[Ks][1]);
        bf8 Bl = mk_bl0(fl[Ks][0], fl[Ks][1]);
        #pragma unroll
        for (int Mi = 0; Mi < 4; ++Mi) {
            u4 w = ap[(Ks*4+Mi)*64 + lane];
            acc[Mi] = mfma2(acc[Mi], afrag(w), Bh, Bl);
        }
    }
}

// Prep: weight pack (blocks 0..275) + cproj AND rbias (blocks 276..531).
// A^T frag (Mi,Ks): lane L holds W[k=16Ks+4(L>>4)+j][m=16Mi+(L&15)], j=0..3.
__global__ void prep_kernel(const float* __restrict__ Wt, const float* __restrict__ W1,
                            const float* __restrict__ W2, const float* __restrict__ Wg,
                            const float* __restrict__ Wp, const float* __restrict__ Ws,
                            const float* __restrict__ ctx, const float* __restrict__ Wctx,
                            const float* __restrict__ bp,
                            u4* __restrict__ wtp, u4* __restrict__ bigp,
                            u4* __restrict__ wsp, float* __restrict__ cproj,
                            float* __restrict__ rbias) {
    if (blockIdx.x >= 276) {
        __shared__ float cp[4][64];
        int sub = threadIdx.x >> 6, d = threadIdx.x & 63;
        int bn = (blockIdx.x - 276) * 4 + sub;
        int b = bn >> 4, n = bn & 15;
        const float* __restrict__ wc = Wctx + n * DD * DD;
        const float* __restrict__ c  = ctx + b * DD;
        float acc = 0.f;
        #pragma unroll 8
        for (int k = 0; k < DD; ++k) acc += c[k] * wc[k * DD + d];
        cproj[bn * DD + d] = acc;
        cp[sub][d] = acc;
        __syncthreads();
        const float* __restrict__ wp = Wp + n * DD * DD;
        float r = bp[n * DD + d];
        #pragma unroll 8
        for (int k = 0; k < DD; ++k) r -= cp[sub][k] * wp[k * DD + d];
        rbias[bn * DD + d] = r;
        return;
    }
    int t = blockIdx.x * 256 + threadIdx.x;
    float v0, v1, v2, v3; u4* dst;
    if (t < 65536) {
        int lane = t & 63, Mi = (t>>6)&3, Ks = (t>>8)&3, mat = (t>>10)&3, var = t>>12;
        const float* W = (mat==0) ? Wp : (mat==1) ? W1 : (mat==2) ? W2 : Wg;
        const float* src = W + var*4096;
        int m = 16*Mi + (lane&15), k0 = 16*Ks + 4*(lane>>4);
        v0 = src[(k0+0)*64+m]; v1 = src[(k0+1)*64+m];
        v2 = src[(k0+2)*64+m]; v3 = src[(k0+3)*64+m];
        dst = bigp + ((var*4+mat)*16 + Ks*4 + Mi)*64 + lane;
    } else if (t < 65536+4096) {
        int r = t - 65536;
        int lane = r & 63, Mi = (r>>6)&3, var = r>>8;
        int m = 16*Mi + (lane&15), k0 = 4*(lane>>4);
        const float* src = Wt + var*1024;
        v0 = src[(k0+0)*64+m]; v1 = src[(k0+1)*64+m];
        v2 = src[(k0+2)*64+m]; v3 = src[(k0+3)*64+m];
        dst = wtp + (var*4+Mi)*64 + lane;
    } else if (t < 65536+4096+1024) {
        int r = t - 69632;
        int lane = r & 63, Ks = r >> 6;
        int m = lane & 15, k0 = 16*Ks + 4*(lane>>4);
        v0 = Ws[(k0+0)*16+m]; v1 = Ws[(k0+1)*16+m];
        v2 = Ws[(k0+2)*16+m]; v3 = Ws[(k0+3)*16+m];
        dst = wsp + Ks*64 + lane;
    } else return;
    f4 v; v.x=v0; v.y=v1; v.z=v2; v.w=v3;
    unsigned h0,h1,l0,l1; split4(v,h0,h1,l0,l1);
    u4 o; o.x=h0; o.y=h1; o.z=l0; o.w=l1;
    *dst = o;
}

// Main: block = 512 threads = 8 waves, 64 tokens; grid = 512 (2 blocks/CU).
// wave wv: grp = wv&1 (vars 8*grp..8*grp+7), tq = wv>>1 (token quarter, 16 tokens).
// Selection accumulates straight into LDS via ds_add_f32 ([d][tok], stride 68 ->
// quads 2-way bank aliased = free), freeing the 16 persistent sel VGPRs that
// caused R7's ~40MB spill. Logits computed only by grp0 waves (dedup) and
// shared through LDS + one barrier (which also covers the sel zero-init).
#define PSEL_OFF 0          // 2 grp regions x [d=64][stride 68] = 8704 dw
#define WSEL_OFF 8704       // 4 tq x 16 n x 17 = 1088 dw
#define SMEM_DW  9792       // 39168 B

__global__ __launch_bounds__(512, 4)
void vsn_kernel(const float* __restrict__ inp,
                const u4* __restrict__ wtp, const u4* __restrict__ bigp,
                const u4* __restrict__ wsp,
                const float* __restrict__ bt, const float* __restrict__ b1,
                const float* __restrict__ b2, const float* __restrict__ bg,
                const float* __restrict__ rbias,
                const float* __restrict__ gamma_, const float* __restrict__ beta_,
                const float* __restrict__ bs,
                const float* __restrict__ cproj,
                float* __restrict__ out_sel, float* __restrict__ out_w) {
    __shared__ float smem[SMEM_DW];

    const int tid  = threadIdx.x;
    const int lane = tid & 63;
    const int wv   = tid >> 6;
    const int grp  = wv & 1;
    const int tq   = wv >> 1;
    const int qd   = lane >> 4;
    const int l15  = lane & 15;
    const int tile0 = blockIdx.x * 64;
    const int b     = blockIdx.x >> 3;          // tile0 / NT
    const int tok0  = tile0 + tq * 16;

    const float* row = inp + (size_t)(tok0 + l15) * FF;   // my token's feature row

    // zero selection accumulators (both grp regions)
    for (int i = tid; i < 8704; i += 512) smem[PSEL_OFF + i] = 0.f;

    // ------------- logits via MFMA + softmax: grp0 waves only (dedup) -------
    if (grp == 0) {
        f4 lacc = *(const f4*)(bs + 4*qd);      // n = 4*qd + reg
        #pragma unroll 4
        for (int Ks = 0; Ks < 16; ++Ks) {
            u4 w = wsp[Ks*64 + lane];
            f4 v = *(const f4*)(row + 16*Ks + 4*qd);
            unsigned h0,h1,l0,l1;
            split4f(v,h0,h1,l0,l1);
            lacc = mfma2(lacc, afrag(w), mk_bhh(h0,h1), mk_bl0(l0,l1));
        }
        float mx = fmaxf(fmaxf(lacc.x,lacc.y), fmaxf(lacc.z,lacc.w));
        mx = fmaxf(mx, __shfl_xor(mx, 16));
        mx = fmaxf(mx, __shfl_xor(mx, 32));
        float e0 = __expf(lacc.x-mx), e1 = __expf(lacc.y-mx);
        float e2 = __expf(lacc.z-mx), e3 = __expf(lacc.w-mx);
        float s = e0+e1+e2+e3;
        s += __shfl_xor(s, 16);
        s += __shfl_xor(s, 32);
        float rs = 1.f / s;
        e0 *= rs; e1 *= rs; e2 *= rs; e3 *= rs;
        int base = WSEL_OFF + tq*272 + (4*qd)*17 + l15;
        smem[base + 0*17] = e0;
        smem[base + 1*17] = e1;
        smem[base + 2*17] = e2;
        smem[base + 3*17] = e3;
        f4 o; o.x=e0; o.y=e1; o.z=e2; o.w=e3;
        *(f4*)(out_w + (size_t)(tok0 + l15)*16 + 4*qd) = o;
    }
    __syncthreads();   // publishes wsel AND the zeroed sel regions

    // ---------------- per-variable GRN chain (8 vars per wave) --------------
    const int selbase = PSEL_OFF + grp*4352 + tq*16 + l15;   // + d*68

    #pragma unroll 1
    for (int vi = 0; vi < 8; ++vi) {
        const int n = grp*8 + vi;
        unsigned fh[4][2], fl[4][2];

        // t = Wt^T @ xv + bt; a = t + cproj; a-frags feed BOTH res and h1.
        f4 tacc[4];
        #pragma unroll
        for (int Mi = 0; Mi < 4; ++Mi) tacc[Mi] = *(const f4*)(bt + n*DD + 16*Mi + 4*qd);
        {
            f4 v = *(const f4*)(row + n*16 + 4*qd);
            unsigned xh0,xh1,xl0,xl1;
            split4f(v, xh0, xh1, xl0, xl1);
            bf8 Bh = mk_bhh(xh0, xh1);
            bf8 Bl = mk_bl0(xl0, xl1);
            #pragma unroll
            for (int Mi = 0; Mi < 4; ++Mi) {
                u4 w = wtp[(n*4+Mi)*64 + lane];
                tacc[Mi] = mfma2(tacc[Mi], afrag(w), Bh, Bl);
            }
        }
        #pragma unroll
        for (int Mi = 0; Mi < 4; ++Mi)
            tacc[Mi] += *(const f4*)(cproj + (size_t)(b*NVAR+n)*DD + 16*Mi + 4*qd);
        acc_to_frags1(tacc, fh, fl);   // a-frags

        // res = Wp^T @ a + rbias  (== Wp^T t + bp; rbias precomputed fp32)
        f4 racc[4];
        #pragma unroll
        for (int Mi = 0; Mi < 4; ++Mi)
            racc[Mi] = *(const f4*)(rbias + (size_t)(b*NVAR+n)*DD + 16*Mi + 4*qd);
        run_stage2(bigp + (n*4 + 0)*1024, lane, fh, fl, racc);

        // h1 = elu(W1^T @ a + b1)
        f4 hacc[4];
        #pragma unroll
        for (int Mi = 0; Mi < 4; ++Mi) hacc[Mi] = *(const f4*)(b1 + n*DD + 16*Mi + 4*qd);
        run_stage2(bigp + (n*4 + 1)*1024, lane, fh, fl, hacc);
        #pragma unroll
        for (int Mi = 0; Mi < 4; ++Mi) {
            f4& v = hacc[Mi];
            v.x = v.x > 0.f ? v.x : (__expf(v.x)-1.f);
            v.y = v.y > 0.f ? v.y : (__expf(v.y)-1.f);
            v.z = v.z > 0.f ? v.z : (__expf(v.z)-1.f);
            v.w = v.w > 0.f ? v.w : (__expf(v.w)-1.f);
        }
        acc_to_frags1(hacc, fh, fl);   // h1 frags

        // h2 = W2^T @ h1 + b2
        #pragma unroll
        for (int Mi = 0; Mi < 4; ++Mi) hacc[Mi] = *(const f4*)(b2 + n*DD + 16*Mi + 4*qd);
        run_stage2(bigp + (n*4 + 2)*1024, lane, fh, fl, hacc);
        acc_to_frags1(hacc, fh, fl);   // h2 frags (fp32 recon from hi+lo below)

        // gate logits = Wg^T @ h2 + bg
        f4 gacc[4];
        #pragma unroll
        for (int Mi = 0; Mi < 4; ++Mi) gacc[Mi] = *(const f4*)(bg + n*DD + 16*Mi + 4*qd);
        run_stage2(bigp + (n*4 + 3)*1024, lane, fh, fl, gacc);

        // z = sigmoid(g)*h2 + res
        f4 z[4];
        #pragma unroll
        for (int Mi = 0; Mi < 4; ++Mi) {
            float h2x = bflo(fh[Mi][0]) + bflo(fl[Mi][0]);
            float h2y = bfhi(fh[Mi][0]) + bfhi(fl[Mi][0]);
            float h2z = bflo(fh[Mi][1]) + bflo(fl[Mi][1]);
            float h2w = bfhi(fh[Mi][1]) + bfhi(fl[Mi][1]);
            f4 gv = gacc[Mi];
            z[Mi].x = h2x / (1.f+__expf(-gv.x)) + racc[Mi].x;
            z[Mi].y = h2y / (1.f+__expf(-gv.y)) + racc[Mi].y;
            z[Mi].z = h2z / (1.f+__expf(-gv.z)) + racc[Mi].z;
            z[Mi].w = h2w / (1.f+__expf(-gv.w)) + racc[Mi].w;
        }
        // LayerNorm over d (16 in-lane + cross-quad butterfly)
        float s = 0.f;
        #pragma unroll
        for (int Mi = 0; Mi < 4; ++Mi) s += z[Mi].x + z[Mi].y + z[Mi].z + z[Mi].w;
        s += __shfl_xor(s, 16);
        s += __shfl_xor(s, 32);
        float mu = s * (1.f/64.f);
        float q = 0.f;
        #pragma unroll
        for (int Mi = 0; Mi < 4; ++Mi) {
            float dx = z[Mi].x - mu; q += dx*dx;
            dx = z[Mi].y - mu; q += dx*dx;
            dx = z[Mi].z - mu; q += dx*dx;
            dx = z[Mi].w - mu; q += dx*dx;
        }
        q += __shfl_xor(q, 16);
        q += __shfl_xor(q, 32);
        float rstd = rsqrtf(q*(1.f/64.f) + LN_EPS);

        float wn = smem[WSEL_OFF + tq*272 + n*17 + l15];
        #pragma unroll
        for (int Mi = 0; Mi < 4; ++Mi) {
            f4 gm = *(const f4*)(gamma_ + n*DD + 16*Mi + 4*qd);
            f4 bb = *(const f4*)(beta_  + n*DD + 16*Mi + 4*qd);
            int d0 = 16*Mi + 4*qd;
            atomicAdd(&smem[selbase + (d0+0)*68], wn*((z[Mi].x-mu)*rstd*gm.x + bb.x));
            atomicAdd(&smem[selbase + (d0+1)*68], wn*((z[Mi].y-mu)*rstd*gm.y + bb.y));
            atomicAdd(&smem[selbase + (d0+2)*68], wn*((z[Mi].z-mu)*rstd*gm.z + bb.z));
            atomicAdd(&smem[selbase + (d0+3)*68], wn*((z[Mi].w-mu)*rstd*gm.w + bb.w));
        }
    }

    __syncthreads();
    {
        int tokloc = tid >> 3;            // 0..63 (the 64 tokens of this tile)
        int d0 = (tid & 7) * 8;
        f4 o0, o1;
        #pragma unroll
        for (int j = 0; j < 4; ++j) {
            o0[j] = smem[PSEL_OFF + (d0+j)*68 + tokloc]
                  + smem[PSEL_OFF + 4352 + (d0+j)*68 + tokloc];
            o1[j] = smem[PSEL_OFF + (d0+4+j)*68 + tokloc]
                  + smem[PSEL_OFF + 4352 + (d0+4+j)*68 + tokloc];
        }
        float* po = out_sel + (size_t)(tile0+tokloc)*DD + d0;
        *(f4*)po     = o0;
        *(f4*)(po+4) = o1;
    }
}

extern "C" void kernel_launch(void* const* d_in, const int* in_sizes, int n_in,
                              void* d_out, int out_size, void* d_ws, size_t ws_size,
                              hipStream_t stream) {
    const float* inp  = (const float*)d_in[0];
    const float* ctx  = (const float*)d_in[1];
    const float* Wt   = (const float*)d_in[2];
    const float* bt   = (const float*)d_in[3];
    const float* Wctx = (const float*)d_in[4];
    const float* W1   = (const float*)d_in[5];
    const float* b1   = (const float*)d_in[6];
    const float* W2   = (const float*)d_in[7];
    const float* b2   = (const float*)d_in[8];
    const float* Wg   = (const float*)d_in[9];
    const float* bg   = (const float*)d_in[10];
    const float* Wp   = (const float*)d_in[11];
    const float* bp   = (const float*)d_in[12];
    const float* gm   = (const float*)d_in[13];
    const float* bt2  = (const float*)d_in[14];
    const float* Ws   = (const float*)d_in[15];
    const float* bs   = (const float*)d_in[16];

    float* out_sel = (float*)d_out;
    float* out_w   = out_sel + (size_t)BT * DD;

    char* ws = (char*)d_ws;
    float* cproj = (float*)(ws + CPROJ_OFF);
    float* rbias = (float*)(ws + RBIAS_OFF);
    u4* wtp  = (u4*)(ws + WTP_OFF);
    u4* bigp = (u4*)(ws + BIGP_OFF);
    u4* wsp  = (u4*)(ws + WSP_OFF);

    prep_kernel<<<532, 256, 0, stream>>>(Wt, W1, W2, Wg, Wp, Ws, ctx, Wctx, bp,
                                         wtp, bigp, wsp, cproj, rbias);
    vsn_kernel<<<BT / 64, 512, 0, stream>>>(inp, wtp, bigp, wsp,
                                            bt, b1, b2, bg, rbias, gm, bt2, bs,
                                            cproj, out_sel, out_w);
}

// Round 9
// 228.322 us; speedup vs baseline: 1.3399x; 1.3399x over previous
//
#include <hip/hip_runtime.h>
#include <math.h>

#define NB 64
#define NT 512
#define NVAR 16
#define VDIM 16
#define DD 64
#define FF 256
#define BT (NB*NT)
#define LN_EPS 1e-3f
#define LOG2E 1.4426950408889634f

typedef __attribute__((ext_vector_type(8))) short bf8;   // 8 bf16 = one MFMA A/B operand
typedef __attribute__((ext_vector_type(4))) float f4;
typedef __attribute__((ext_vector_type(4))) int i4;
typedef __attribute__((ext_vector_type(4))) unsigned u4;

// ---- ws layout (bytes) ----
#define CPROJ_OFF   0                        // 64*16*64 f32 = 256KB
#define RBIAS_OFF   262144                   // 64*16*64 f32 = 256KB  (bp - cproj@Wp)
#define WTP_OFF     524288                   // 16 vars x 4 frags x 64 x 16B = 64KB
#define BIGP_OFF    (524288+65536)           // 16 vars x 4 mats x 16 frags x 64 x 16B = 1MB
#define WSP_OFF     (524288+65536+1048576)   // 16 frags x 64 x 16B = 16KB
#define BGS_OFF     (524288+65536+1048576+16384) // bg*log2e, 16*64 f32 = 4KB
// mats: 0=Wp 1=W1 2=W2 3=Wg(prescaled by log2e)

// ---- precise RNE split (prep-time only) ----
__device__ __forceinline__ void split1(float x, unsigned &hb, float &lo) {
    unsigned u = __builtin_bit_cast(unsigned, x);
    unsigned r = u + 0x7fffu + ((u >> 16) & 1u);
    hb = r >> 16;
    lo = x - __builtin_bit_cast(float, r & 0xffff0000u);
}
__device__ __forceinline__ unsigned rnepk(float x, float y) {
    unsigned a = __builtin_bit_cast(unsigned, x);
    unsigned b = __builtin_bit_cast(unsigned, y);
    a = a + 0x7fffu + ((a >> 16) & 1u);
    b = b + 0x7fffu + ((b >> 16) & 1u);
    return (a >> 16) | (b & 0xffff0000u);
}
__device__ __forceinline__ void split4(f4 v, unsigned &h0, unsigned &h1,
                                       unsigned &l0, unsigned &l1) {
    unsigned b0,b1,b2,b3; float q0,q1,q2,q3;
    split1(v.x,b0,q0); split1(v.y,b1,q1); split1(v.z,b2,q2); split1(v.w,b3,q3);
    h0 = b0 | (b1<<16); h1 = b2 | (b3<<16);
    l0 = rnepk(q0,q1); l1 = rnepk(q2,q3);
}
// ---- fast truncation split (hot path): hi = trunc(x), lo = trunc(x - hi) ----
// hi rel err <= 2^-8 but lo captures the residual exactly (then bf16-trunc:
// net recon err ~2^-16; dropped Wl*xl term ~2^-17 — well under threshold).
__device__ __forceinline__ void split4f(f4 v, unsigned &h0, unsigned &h1,
                                        unsigned &l0, unsigned &l1) {
    unsigned a0 = __builtin_bit_cast(unsigned, v.x);
    unsigned a1 = __builtin_bit_cast(unsigned, v.y);
    unsigned a2 = __builtin_bit_cast(unsigned, v.z);
    unsigned a3 = __builtin_bit_cast(unsigned, v.w);
    unsigned m0 = a0 & 0xffff0000u, m1 = a1 & 0xffff0000u;
    unsigned m2 = a2 & 0xffff0000u, m3 = a3 & 0xffff0000u;
    h0 = (a0 >> 16) | m1;
    h1 = (a2 >> 16) | m3;
    float lx = v.x - __builtin_bit_cast(float, m0);
    float ly = v.y - __builtin_bit_cast(float, m1);
    float lz = v.z - __builtin_bit_cast(float, m2);
    float lw = v.w - __builtin_bit_cast(float, m3);
    l0 = (__builtin_bit_cast(unsigned, lx) >> 16) |
         (__builtin_bit_cast(unsigned, ly) & 0xffff0000u);
    l1 = (__builtin_bit_cast(unsigned, lz) >> 16) |
         (__builtin_bit_cast(unsigned, lw) & 0xffff0000u);
}
// A operand = packed u4 verbatim: slots 0..3 = W_hi, slots 4..7 = W_lo
__device__ __forceinline__ bf8 afrag(u4 w) { return __builtin_bit_cast(bf8, w); }
// B operands for the 2-mfma split: [x_h|x_h] and [x_l|0]
__device__ __forceinline__ bf8 mk_bhh(unsigned h0, unsigned h1) {
    i4 t; t.x = (int)h0; t.y = (int)h1; t.z = (int)h0; t.w = (int)h1;
    return __builtin_bit_cast(bf8, t);
}
__device__ __forceinline__ bf8 mk_bl0(unsigned l0, unsigned l1) {
    i4 t; t.x = (int)l0; t.y = (int)l1; t.z = 0; t.w = 0;
    return __builtin_bit_cast(bf8, t);
}
__device__ __forceinline__ float bflo(unsigned w){ return __builtin_bit_cast(float, w<<16); }
__device__ __forceinline__ float bfhi(unsigned w){ return __builtin_bit_cast(float, w & 0xffff0000u); }

// 2-mfma split: A=[Wh|Wl] with Bh=[xh|xh] gives Wh*xh + Wl*xh; Bl=[xl|0] adds Wh*xl.
__device__ __forceinline__ f4 mfma2(f4 acc, bf8 Af, bf8 Bh, bf8 Bl) {
    acc = __builtin_amdgcn_mfma_f32_16x16x32_bf16(Af, Bh, acc, 0,0,0);
    acc = __builtin_amdgcn_mfma_f32_16x16x32_bf16(Af, Bl, acc, 0,0,0);
    return acc;
}

// acc (C-layout) -> B-operand frags of the next stage (pure in-lane repack)
__device__ __forceinline__ void acc_to_frags1(const f4 acc[4],
        unsigned fh[4][2], unsigned fl[4][2]) {
    #pragma unroll
    for (int Ks = 0; Ks < 4; ++Ks)
        split4f(acc[Ks], fh[Ks][0], fh[Ks][1], fl[Ks][0], fl[Ks][1]);
}
// One 64x64 GEMM-stage: acc[Mi] += Wpack^T . Bfrags  (2-mfma split)
__device__ __forceinline__ void run_stage2(const u4* __restrict__ ap, int lane,
        const unsigned fh[4][2], const unsigned fl[4][2], f4 acc[4]) {
    #pragma unroll 2
    for (int Ks = 0; Ks < 4; ++Ks) {
        bf8 Bh = mk_bhh(fh[Ks][0], fh[Ks][1]);
        bf8 Bl = mk_bl0(fl[Ks][0], fl[Ks][1]);
        #pragma unroll
        for (int Mi = 0; Mi < 4; ++Mi) {
            u4 w = ap[(Ks*4+Mi)*64 + lane];
            acc[Mi] = mfma2(acc[Mi], afrag(w), Bh, Bl);
        }
    }
}

// Prep: weight pack + bg scaling (blocks 0..279) + cproj/rbias (blocks 280..535).
// A^T frag (Mi,Ks): lane L holds W[k=16Ks+4(L>>4)+j][m=16Mi+(L&15)], j=0..3.
// Wg (mat==3) is prescaled by log2e so the gate uses native exp2.
__global__ void prep_kernel(const float* __restrict__ Wt, const float* __restrict__ W1,
                            const float* __restrict__ W2, const float* __restrict__ Wg,
                            const float* __restrict__ Wp, const float* __restrict__ Ws,
                            const float* __restrict__ ctx, const float* __restrict__ Wctx,
                            const float* __restrict__ bp, const float* __restrict__ bg,
                            u4* __restrict__ wtp, u4* __restrict__ bigp,
                            u4* __restrict__ wsp, float* __restrict__ cproj,
                            float* __restrict__ rbias, float* __restrict__ bgs) {
    if (blockIdx.x >= 280) {
        __shared__ float cp[4][64];
        int sub = threadIdx.x >> 6, d = threadIdx.x & 63;
        int bn = (blockIdx.x - 280) * 4 + sub;
        int b = bn >> 4, n = bn & 15;
        const float* __restrict__ wc = Wctx + n * DD * DD;
        const float* __restrict__ c  = ctx + b * DD;
        float acc = 0.f;
        #pragma unroll 8
        for (int k = 0; k < DD; ++k) acc += c[k] * wc[k * DD + d];
        cproj[bn * DD + d] = acc;
        cp[sub][d] = acc;
        __syncthreads();
        const float* __restrict__ wp = Wp + n * DD * DD;
        float r = bp[n * DD + d];
        #pragma unroll 8
        for (int k = 0; k < DD; ++k) r -= cp[sub][k] * wp[k * DD + d];
        rbias[bn * DD + d] = r;
        return;
    }
    int t = blockIdx.x * 256 + threadIdx.x;
    float v0, v1, v2, v3; u4* dst;
    if (t < 65536) {
        int lane = t & 63, Mi = (t>>6)&3, Ks = (t>>8)&3, mat = (t>>10)&3, var = t>>12;
        const float* W = (mat==0) ? Wp : (mat==1) ? W1 : (mat==2) ? W2 : Wg;
        const float* src = W + var*4096;
        int m = 16*Mi + (lane&15), k0 = 16*Ks + 4*(lane>>4);
        float sc = (mat == 3) ? LOG2E : 1.f;
        v0 = sc*src[(k0+0)*64+m]; v1 = sc*src[(k0+1)*64+m];
        v2 = sc*src[(k0+2)*64+m]; v3 = sc*src[(k0+3)*64+m];
        dst = bigp + ((var*4+mat)*16 + Ks*4 + Mi)*64 + lane;
    } else if (t < 65536+4096) {
        int r = t - 65536;
        int lane = r & 63, Mi = (r>>6)&3, var = r>>8;
        int m = 16*Mi + (lane&15), k0 = 4*(lane>>4);
        const float* src = Wt + var*1024;
        v0 = src[(k0+0)*64+m]; v1 = src[(k0+1)*64+m];
        v2 = src[(k0+2)*64+m]; v3 = src[(k0+3)*64+m];
        dst = wtp + (var*4+Mi)*64 + lane;
    } else if (t < 65536+4096+1024) {
        int r = t - 69632;
        int lane = r & 63, Ks = r >> 6;
        int m = lane & 15, k0 = 16*Ks + 4*(lane>>4);
        v0 = Ws[(k0+0)*16+m]; v1 = Ws[(k0+1)*16+m];
        v2 = Ws[(k0+2)*16+m]; v3 = Ws[(k0+3)*16+m];
        dst = wsp + Ks*64 + lane;
    } else if (t < 65536+4096+1024+1024) {
        int r = t - 70656;
        bgs[r] = bg[r] * LOG2E;
        return;
    } else return;
    f4 v; v.x=v0; v.y=v1; v.z=v2; v.w=v3;
    unsigned h0,h1,l0,l1; split4(v,h0,h1,l0,l1);
    u4 o; o.x=h0; o.y=h1; o.z=l0; o.w=l1;
    *dst = o;
}

// Main: block = 512 threads = 8 waves, 64 tokens; grid = 512 (2 blocks/CU).
// wave wv: grp = wv&1 (vars 8*grp..8*grp+7), tq = wv>>1 (token quarter, 16 tokens).
// R7 structure restored: sel accumulates in VGPRs (spills are latency-hidden and
// cheaper than R8's lockstep barrier + LDS atomics — measured 187 vs 230 us),
// logits computed redundantly by both grp waves (keeps waves skewed, no barrier).
#define PSEL_OFF 0          // 128 rows (grp*64+tq*16+l15) x 68 dw = 8704 dw
#define WSEL_OFF 8704       // 4 tq x 16 n x 17 = 1088 dw
#define SMEM_DW  9792       // 39168 B

__global__ __launch_bounds__(512, 4)
void vsn_kernel(const float* __restrict__ inp,
                const u4* __restrict__ wtp, const u4* __restrict__ bigp,
                const u4* __restrict__ wsp,
                const float* __restrict__ bt, const float* __restrict__ b1,
                const float* __restrict__ b2, const float* __restrict__ bgs,
                const float* __restrict__ rbias,
                const float* __restrict__ gamma_, const float* __restrict__ beta_,
                const float* __restrict__ bs,
                const float* __restrict__ cproj,
                float* __restrict__ out_sel, float* __restrict__ out_w) {
    __shared__ float smem[SMEM_DW];

    const int tid  = threadIdx.x;
    const int lane = tid & 63;
    const int wv   = tid >> 6;
    const int grp  = wv & 1;
    const int tq   = wv >> 1;
    const int qd   = lane >> 4;
    const int l15  = lane & 15;
    const int tile0 = blockIdx.x * 64;
    const int b     = blockIdx.x >> 3;          // tile0 / NT
    const int tok0  = tile0 + tq * 16;

    const float* row = inp + (size_t)(tok0 + l15) * FF;   // my token's feature row

    // ---------------- logits via MFMA + softmax (per wave, 16 tokens) -------
    {
        f4 lacc = *(const f4*)(bs + 4*qd);      // n = 4*qd + reg
        #pragma unroll 4
        for (int Ks = 0; Ks < 16; ++Ks) {
            u4 w = wsp[Ks*64 + lane];
            f4 v = *(const f4*)(row + 16*Ks + 4*qd);
            unsigned h0,h1,l0,l1;
            split4f(v,h0,h1,l0,l1);
            lacc = mfma2(lacc, afrag(w), mk_bhh(h0,h1), mk_bl0(l0,l1));
        }
        float mx = fmaxf(fmaxf(lacc.x,lacc.y), fmaxf(lacc.z,lacc.w));
        mx = fmaxf(mx, __shfl_xor(mx, 16));
        mx = fmaxf(mx, __shfl_xor(mx, 32));
        float e0 = __expf(lacc.x-mx), e1 = __expf(lacc.y-mx);
        float e2 = __expf(lacc.z-mx), e3 = __expf(lacc.w-mx);
        float s = e0+e1+e2+e3;
        s += __shfl_xor(s, 16);
        s += __shfl_xor(s, 32);
        float rs = __builtin_amdgcn_rcpf(s);
        e0 *= rs; e1 *= rs; e2 *= rs; e3 *= rs;
        // both grp waves of a tq write identical bits -> benign duplicate
        int base = WSEL_OFF + tq*272 + (4*qd)*17 + l15;
        smem[base + 0*17] = e0;
        smem[base + 1*17] = e1;
        smem[base + 2*17] = e2;
        smem[base + 3*17] = e3;
        if (grp == 0) {
            f4 o; o.x=e0; o.y=e1; o.z=e2; o.w=e3;
            *(f4*)(out_w + (size_t)(tok0 + l15)*16 + 4*qd) = o;
        }
    }

    // ---------------- per-variable GRN chain (8 vars per wave) --------------
    f4 sel[4];
    #pragma unroll
    for (int Mi = 0; Mi < 4; ++Mi) sel[Mi] = (f4)0.f;

    #pragma unroll 1
    for (int vi = 0; vi < 8; ++vi) {
        const int n = grp*8 + vi;
        unsigned fh[4][2], fl[4][2];

        // t = Wt^T @ xv + bt; a = t + cproj; a-frags feed BOTH res and h1.
        f4 tacc[4];
        #pragma unroll
        for (int Mi = 0; Mi < 4; ++Mi) tacc[Mi] = *(const f4*)(bt + n*DD + 16*Mi + 4*qd);
        {
            f4 v = *(const f4*)(row + n*16 + 4*qd);
            unsigned xh0,xh1,xl0,xl1;
            split4f(v, xh0, xh1, xl0, xl1);
            bf8 Bh = mk_bhh(xh0, xh1);
            bf8 Bl = mk_bl0(xl0, xl1);
            #pragma unroll
            for (int Mi = 0; Mi < 4; ++Mi) {
                u4 w = wtp[(n*4+Mi)*64 + lane];
                tacc[Mi] = mfma2(tacc[Mi], afrag(w), Bh, Bl);
            }
        }
        #pragma unroll
        for (int Mi = 0; Mi < 4; ++Mi)
            tacc[Mi] += *(const f4*)(cproj + (size_t)(b*NVAR+n)*DD + 16*Mi + 4*qd);
        acc_to_frags1(tacc, fh, fl);   // a-frags

        // res = Wp^T @ a + rbias  (== Wp^T t + bp; rbias precomputed fp32)
        f4 racc[4];
        #pragma unroll
        for (int Mi = 0; Mi < 4; ++Mi)
            racc[Mi] = *(const f4*)(rbias + (size_t)(b*NVAR+n)*DD + 16*Mi + 4*qd);
        run_stage2(bigp + (n*4 + 0)*1024, lane, fh, fl, racc);

        // h1 = elu(W1^T @ a + b1)
        f4 hacc[4];
        #pragma unroll
        for (int Mi = 0; Mi < 4; ++Mi) hacc[Mi] = *(const f4*)(b1 + n*DD + 16*Mi + 4*qd);
        run_stage2(bigp + (n*4 + 1)*1024, lane, fh, fl, hacc);
        #pragma unroll
        for (int Mi = 0; Mi < 4; ++Mi) {
            f4& v = hacc[Mi];
            v.x = v.x > 0.f ? v.x : (__expf(v.x)-1.f);
            v.y = v.y > 0.f ? v.y : (__expf(v.y)-1.f);
            v.z = v.z > 0.f ? v.z : (__expf(v.z)-1.f);
            v.w = v.w > 0.f ? v.w : (__expf(v.w)-1.f);
        }
        acc_to_frags1(hacc, fh, fl);   // h1 frags

        // h2 = W2^T @ h1 + b2
        #pragma unroll
        for (int Mi = 0; Mi < 4; ++Mi) hacc[Mi] = *(const f4*)(b2 + n*DD + 16*Mi + 4*qd);
        run_stage2(bigp + (n*4 + 2)*1024, lane, fh, fl, hacc);
        acc_to_frags1(hacc, fh, fl);   // h2 frags (fp32 recon from hi+lo below)

        // gate logits (pre-scaled by log2e) = Wg'^T @ h2 + bgs
        f4 gacc[4];
        #pragma unroll
        for (int Mi = 0; Mi < 4; ++Mi) gacc[Mi] = *(const f4*)(bgs + n*DD + 16*Mi + 4*qd);
        run_stage2(bigp + (n*4 + 3)*1024, lane, fh, fl, gacc);

        // z = h2 * rcp(1 + exp2(-g')) + res
        f4 z[4];
        #pragma unroll
        for (int Mi = 0; Mi < 4; ++Mi) {
            float h2x = bflo(fh[Mi][0]) + bflo(fl[Mi][0]);
            float h2y = bfhi(fh[Mi][0]) + bfhi(fl[Mi][0]);
            float h2z = bflo(fh[Mi][1]) + bflo(fl[Mi][1]);
            float h2w = bfhi(fh[Mi][1]) + bfhi(fl[Mi][1]);
            f4 gv = gacc[Mi];
            z[Mi].x = h2x * __builtin_amdgcn_rcpf(1.f + __builtin_amdgcn_exp2f(-gv.x)) + racc[Mi].x;
            z[Mi].y = h2y * __builtin_amdgcn_rcpf(1.f + __builtin_amdgcn_exp2f(-gv.y)) + racc[Mi].y;
            z[Mi].z = h2z * __builtin_amdgcn_rcpf(1.f + __builtin_amdgcn_exp2f(-gv.z)) + racc[Mi].z;
            z[Mi].w = h2w * __builtin_amdgcn_rcpf(1.f + __builtin_amdgcn_exp2f(-gv.w)) + racc[Mi].w;
        }
        // LayerNorm over d (16 in-lane + cross-quad butterfly)
        float s = 0.f;
        #pragma unroll
        for (int Mi = 0; Mi < 4; ++Mi) s += z[Mi].x + z[Mi].y + z[Mi].z + z[Mi].w;
        s += __shfl_xor(s, 16);
        s += __shfl_xor(s, 32);
        float mu = s * (1.f/64.f);
        float q = 0.f;
        #pragma unroll
        for (int Mi = 0; Mi < 4; ++Mi) {
            float dx = z[Mi].x - mu; q += dx*dx;
            dx = z[Mi].y - mu; q += dx*dx;
            dx = z[Mi].z - mu; q += dx*dx;
            dx = z[Mi].w - mu; q += dx*dx;
        }
        q += __shfl_xor(q, 16);
        q += __shfl_xor(q, 32);
        float rstd = rsqrtf(q*(1.f/64.f) + LN_EPS);

        float wn = smem[WSEL_OFF + tq*272 + n*17 + l15];
        #pragma unroll
        for (int Mi = 0; Mi < 4; ++Mi) {
            f4 gm = *(const f4*)(gamma_ + n*DD + 16*Mi + 4*qd);
            f4 bb = *(const f4*)(beta_  + n*DD + 16*Mi + 4*qd);
            sel[Mi].x += wn*((z[Mi].x-mu)*rstd*gm.x + bb.x);
            sel[Mi].y += wn*((z[Mi].y-mu)*rstd*gm.y + bb.y);
            sel[Mi].z += wn*((z[Mi].z-mu)*rstd*gm.z + bb.z);
            sel[Mi].w += wn*((z[Mi].w-mu)*rstd*gm.w + bb.w);
        }
    }

    // partial sel -> LDS row (grp*64 + tq*16 + l15), stride 68 dw (17x16B, aligned)
    {
        int base = PSEL_OFF + (grp*64 + tq*16 + l15)*68;
        #pragma unroll
        for (int Mi = 0; Mi < 4; ++Mi)
            *(f4*)&smem[base + 16*Mi + 4*qd] = sel[Mi];
    }
    __syncthreads();
    {
        int tokloc = tid >> 3;            // 0..63 (the 64 tokens of this tile)
        int d0 = (tid & 7) * 8;
        int rbase = PSEL_OFF + tokloc*68 + d0;
        f4 a0 = *(f4*)&smem[rbase];
        f4 a1 = *(f4*)&smem[rbase + 4];
        f4 b0 = *(f4*)&smem[rbase + 64*68];
        f4 b1v = *(f4*)&smem[rbase + 64*68 + 4];
        float* po = out_sel + (size_t)(tile0+tokloc)*DD + d0;
        *(f4*)po     = a0 + b0;
        *(f4*)(po+4) = a1 + b1v;
    }
}

extern "C" void kernel_launch(void* const* d_in, const int* in_sizes, int n_in,
                              void* d_out, int out_size, void* d_ws, size_t ws_size,
                              hipStream_t stream) {
    const float* inp  = (const float*)d_in[0];
    const float* ctx  = (const float*)d_in[1];
    const float* Wt   = (const float*)d_in[2];
    const float* bt   = (const float*)d_in[3];
    const float* Wctx = (const float*)d_in[4];
    const float* W1   = (const float*)d_in[5];
    const float* b1   = (const float*)d_in[6];
    const float* W2   = (const float*)d_in[7];
    const float* b2   = (const float*)d_in[8];
    const float* Wg   = (const float*)d_in[9];
    const float* bg   = (const float*)d_in[10];
    const float* Wp   = (const float*)d_in[11];
    const float* bp   = (const float*)d_in[12];
    const float* gm   = (const float*)d_in[13];
    const float* bt2  = (const float*)d_in[14];
    const float* Ws   = (const float*)d_in[15];
    const float* bs   = (const float*)d_in[16];

    float* out_sel = (float*)d_out;
    float* out_w   = out_sel + (size_t)BT * DD;

    char* ws = (char*)d_ws;
    float* cproj = (float*)(ws + CPROJ_OFF);
    float* rbias = (float*)(ws + RBIAS_OFF);
    u4* wtp  = (u4*)(ws + WTP_OFF);
    u4* bigp = (u4*)(ws + BIGP_OFF);
    u4* wsp  = (u4*)(ws + WSP_OFF);
    float* bgs = (float*)(ws + BGS_OFF);

    prep_kernel<<<536, 256, 0, stream>>>(Wt, W1, W2, Wg, Wp, Ws, ctx, Wctx, bp, bg,
                                         wtp, bigp, wsp, cproj, rbias, bgs);
    vsn_kernel<<<BT / 64, 512, 0, stream>>>(inp, wtp, bigp, wsp,
                                            bt, b1, b2, bgs, rbias, gm, bt2, bs,
                                            cproj, out_sel, out_w);
}